// Round 13
// baseline (245.440 us; speedup 1.0000x reference)
//
#include <hip/hip_runtime.h>
#include <math.h>
#include <stdint.h>

#define BATCH 64
#define N_OBJ 32
#define NP 8732
#define NC 81
#define THRESH 0.5f

// ---------------------------------------------------------------------------
// ws layout:
//   ovp    : float[BATCH*NP]   best IoU per (image, prior)
//   objp   : int  [BATCH*NP]   argmax object per (image, prior)
//   ce_neg : float[BATCH*NP]   CE of negatives (0 at positives)
//   pfo    : int  [BATCH*N_OBJ] argmax prior per (image, object)
//   n_pos  : int  [BATCH]
//   scal   : float[3]          {conf_pos, conf_hard_neg, loc_sum}
// ---------------------------------------------------------------------------

__device__ __forceinline__ float iou_box_prior(float x1, float y1, float x2, float y2,
                                               float areaA, float4 pr, float areaB) {
    float iw = fminf(x2, pr.z) - fmaxf(x1, pr.x); iw = fmaxf(iw, 0.f);
    float ih = fminf(y2, pr.w) - fmaxf(y1, pr.y); ih = fmaxf(ih, 0.f);
    float inter = iw * ih;
    return inter / (areaA + areaB - inter);
}

// per (image, prior): best object (first-occurrence argmax like jnp)
// also zeroes n_pos/scal (completes before k_ce runs)
__global__ void k_match_prior(const float* __restrict__ boxes,
                              const float* __restrict__ priors,
                              float* __restrict__ ovp, int* __restrict__ objp,
                              int* __restrict__ n_pos, float* __restrict__ scal) {
    int i = blockIdx.y;
    int t = threadIdx.x;
    if (blockIdx.x == 0 && i == 0) {
        if (t < BATCH) n_pos[t] = 0;
        if (t < 3) scal[t] = 0.f;
    }
    __shared__ float bx[N_OBJ * 4];
    if (t < N_OBJ * 4) bx[t] = boxes[i * N_OBJ * 4 + t];
    __syncthreads();
    int p = blockIdx.x * blockDim.x + t;
    if (p >= NP) return;
    float4 pr = ((const float4*)priors)[p];
    float areaB = (pr.z - pr.x) * (pr.w - pr.y);
    float best = -1.0f; int bestj = 0;
    #pragma unroll
    for (int j = 0; j < N_OBJ; ++j) {
        float x1 = bx[j * 4 + 0], y1 = bx[j * 4 + 1], x2 = bx[j * 4 + 2], y2 = bx[j * 4 + 3];
        float areaA = (x2 - x1) * (y2 - y1);
        float v = iou_box_prior(x1, y1, x2, y2, areaA, pr, areaB);
        if (v > best) { best = v; bestj = j; }   // strict > keeps FIRST max
    }
    ovp[i * NP + p] = best;
    objp[i * NP + p] = bestj;
}

// per (image, object): best prior (first-index tie-break)
__global__ void k_match_obj(const float* __restrict__ boxes,
                            const float* __restrict__ priors,
                            int* __restrict__ pfo) {
    int j = blockIdx.x, i = blockIdx.y;
    const float* bp = boxes + (i * N_OBJ + j) * 4;
    float x1 = bp[0], y1 = bp[1], x2 = bp[2], y2 = bp[3];
    float areaA = (x2 - x1) * (y2 - y1);
    float best = -1.f; int bestp = NP;
    for (int p = threadIdx.x; p < NP; p += blockDim.x) {
        float4 pr = ((const float4*)priors)[p];
        float areaB = (pr.z - pr.x) * (pr.w - pr.y);
        float v = iou_box_prior(x1, y1, x2, y2, areaA, pr, areaB);
        if (v > best) { best = v; bestp = p; }   // p ascending -> first max kept
    }
    __shared__ float sv[256];
    __shared__ int   si[256];
    int t = threadIdx.x;
    sv[t] = best; si[t] = bestp;
    __syncthreads();
    for (int s = 128; s > 0; s >>= 1) {
        if (t < s) {
            float v2 = sv[t + s]; int i2 = si[t + s];
            if (v2 > sv[t] || (v2 == sv[t] && i2 < si[t])) { sv[t] = v2; si[t] = i2; }
        }
        __syncthreads();
    }
    if (t == 0) pfo[i * N_OBJ + j] = si[0];
}

// sequential last-wins forced matches (matches .at[].set realization)
__global__ void k_force(const int* __restrict__ pfo,
                        float* __restrict__ ovp, int* __restrict__ objp) {
    int i = blockIdx.x * blockDim.x + threadIdx.x;
    if (i >= BATCH) return;
    for (int j = 0; j < N_OBJ; ++j) {
        int p = pfo[i * N_OBJ + j];
        objp[i * NP + p] = j;
        ovp[i * NP + p] = 1.0f;
    }
}

// Deep-MLP CE: 4 lanes/row, each wave owns 4 row-sets of 16 consecutive rows;
// ALL 20 float4 loads issued up-front (20KB in flight per wave, Little's law),
// single exp-sum pass (no max subtraction: scores ~N(0,1), exp never
// overflows; lse = log(sum exp(x)) exactly). Metadata loads overlap the batch.
__global__ void __launch_bounds__(256)
k_ce(const float* __restrict__ scores,
     const float* __restrict__ plocs,
     const float* __restrict__ boxes,
     const int*   __restrict__ labels,
     const float* __restrict__ priors,
     const float* __restrict__ ovp,
     const int*   __restrict__ objp,
     float* __restrict__ ce_neg,
     int* __restrict__ n_pos, float* __restrict__ scal) {
    int i    = blockIdx.y;
    int t    = threadIdx.x;
    int w    = t >> 6;
    int lane = t & 63;
    int g    = lane >> 2;                      // group in wave [0,16)
    int c    = lane & 3;
    int base = blockIdx.x * 256 + w * 16 + g;  // row at k=0; rows: base+64k

    // row pointers (clamped for tail; tail lanes skip writes)
    const float* rowp[4]; int pp[4]; bool ok[4];
    #pragma unroll
    for (int k = 0; k < 4; ++k) {
        int p = base + 64 * k;
        ok[k] = (p < NP);
        pp[k] = ok[k] ? p : (NP - 1);
        rowp[k] = scores + ((size_t)i * NP + pp[k]) * NC;
    }

    // issue all 20 main loads up-front (static indices -> registers)
    float4 v[4][5];
    #pragma unroll
    for (int k = 0; k < 4; ++k)
        #pragma unroll
        for (int j = 0; j < 5; ++j)
            v[k][j] = *reinterpret_cast<const float4*>(rowp[k] + 16 * j + 4 * c);

    // per-row metadata (overlaps the 20 loads above)
    int lab[4]; float slab[4], e80[4]; int obj[4];
    #pragma unroll
    for (int k = 0; k < 4; ++k) {
        int gi = i * NP + pp[k];
        obj[k] = objp[gi];
        float ov = ovp[gi];
        lab[k] = (ov < THRESH) ? 0 : labels[i * N_OBJ + obj[k]];
        slab[k] = (c == 0) ? rowp[k][lab[k]] : 0.f;
        e80[k]  = (c == 0) ? rowp[k][80]    : 0.f;
    }

    #pragma unroll
    for (int k = 0; k < 4; ++k) {
        float s0 = 0.f, s1 = 0.f, s2 = 0.f, s3 = 0.f;
        #pragma unroll
        for (int j = 0; j < 5; ++j) {
            s0 += __expf(v[k][j].x);
            s1 += __expf(v[k][j].y);
            s2 += __expf(v[k][j].z);
            s3 += __expf(v[k][j].w);
        }
        float s = (s0 + s1) + (s2 + s3);
        if (c == 0) s += __expf(e80[k]);
        s += __shfl_xor(s, 1);
        s += __shfl_xor(s, 2);

        if (c == 0 && ok[k]) {
            int gi = i * NP + pp[k];
            float ce = __logf(s) - slab[k];
            if (lab[k] != 0) {
                atomicAdd(&n_pos[i], 1);
                atomicAdd(&scal[0], ce);
                const float* bp = boxes + (i * N_OBJ + obj[k]) * 4;
                float bx1 = bp[0], by1 = bp[1], bx2 = bp[2], by2 = bp[3];
                float bcx = (bx1 + bx2) * 0.5f, bcy = (by1 + by2) * 0.5f;
                float bw = bx2 - bx1, bh = by2 - by1;
                float4 pr = ((const float4*)priors)[pp[k]];
                float g0 = (bcx - pr.x) / (pr.z / 10.0f);
                float g1 = (bcy - pr.y) / (pr.w / 10.0f);
                float g2 = logf(bw / pr.z) * 5.0f;
                float g3 = logf(bh / pr.w) * 5.0f;
                const float* pl = plocs + (size_t)gi * 4;
                float ll = fabsf(pl[0] - g0) + fabsf(pl[1] - g1)
                         + fabsf(pl[2] - g2) + fabsf(pl[3] - g3);
                atomicAdd(&scal[2], ll);
                ce_neg[gi] = 0.f;
            } else {
                ce_neg[gi] = ce;
            }
        }
    }
}

// exact top-k sum per row; row held in registers (35/thread, static unroll),
// 31-pass binary search on the float bit pattern (all ce >= 0)
__global__ void __launch_bounds__(256)
k_topk(const float* __restrict__ ce_neg,
       const int* __restrict__ n_pos, float* __restrict__ scal) {
    int i = blockIdx.x;
    int t = threadIdx.x;
    float x[35];
    #pragma unroll
    for (int j = 0; j < 35; ++j) {
        int p = t + j * 256;
        x[j] = (p < NP) ? ce_neg[i * NP + p] : 0.f;
    }
    int k = 3 * n_pos[i];
    if (k > NP) k = NP;
    if (k <= 0) return;                     // uniform across block

    __shared__ int   cnt_s[4];
    __shared__ float sum_s[4];
    unsigned lo = 0u, hi = 0x7F800001u;     // cnt(lo)=all >= k ; cnt(hi)=0 < k
    while (hi - lo > 1u) {
        unsigned mid = lo + ((hi - lo) >> 1);
        int c = 0;
        #pragma unroll
        for (int j = 0; j < 35; ++j) c += (__float_as_uint(x[j]) >= mid) ? 1 : 0;
        #pragma unroll
        for (int off = 32; off; off >>= 1) c += __shfl_xor(c, off);
        if ((t & 63) == 0) cnt_s[t >> 6] = c;
        __syncthreads();
        int total = cnt_s[0] + cnt_s[1] + cnt_s[2] + cnt_s[3];
        __syncthreads();
        if (total >= k) lo = mid; else hi = mid;
    }
    float vk = __uint_as_float(lo);         // k-th largest (an actual element, or 0)

    float s = 0.f; int c = 0;
    #pragma unroll
    for (int j = 0; j < 35; ++j) {
        float v = x[j];
        if (v > vk) { s += v; c++; }
    }
    #pragma unroll
    for (int off = 32; off; off >>= 1) { s += __shfl_xor(s, off); c += __shfl_xor(c, off); }
    if ((t & 63) == 0) { sum_s[t >> 6] = s; cnt_s[t >> 6] = c; }
    __syncthreads();
    if (t == 0) {
        float st = sum_s[0] + sum_s[1] + sum_s[2] + sum_s[3];
        int   ct = cnt_s[0] + cnt_s[1] + cnt_s[2] + cnt_s[3];
        atomicAdd(&scal[1], st + (float)(k - ct) * vk);
    }
}

__global__ void k_final(const int* __restrict__ n_pos,
                        const float* __restrict__ scal, float* __restrict__ out) {
    int t = threadIdx.x;
    int v = (t < BATCH) ? n_pos[t] : 0;
    #pragma unroll
    for (int off = 32; off; off >>= 1) v += __shfl_xor(v, off);
    if (t == 0) {
        float nf = (float)v;
        out[0] = (scal[1] + scal[0]) / nf + scal[2] / (nf * 4.0f);
    }
}

extern "C" void kernel_launch(void* const* d_in, const int* in_sizes, int n_in,
                              void* d_out, int out_size, void* d_ws, size_t ws_size,
                              hipStream_t stream) {
    const float* plocs  = (const float*)d_in[0];
    const float* scores = (const float*)d_in[1];
    const float* boxes  = (const float*)d_in[2];
    const int*   labels = (const int*)d_in[3];
    const float* priors = (const float*)d_in[4];
    float* out = (float*)d_out;

    char* ws = (char*)d_ws;
    size_t bp = (size_t)BATCH * NP * 4;
    float* ovp    = (float*)(ws);
    int*   objp   = (int*)  (ws + bp);
    float* ce_neg = (float*)(ws + 2 * bp);
    int*   pfo    = (int*)  (ws + 3 * bp);
    int*   n_pos  = pfo + BATCH * N_OBJ;
    float* scal   = (float*)(n_pos + BATCH);

    hipLaunchKernelGGL(k_match_prior, dim3((NP + 255) / 256, BATCH), dim3(256), 0, stream,
                       boxes, priors, ovp, objp, n_pos, scal);
    hipLaunchKernelGGL(k_match_obj, dim3(N_OBJ, BATCH), dim3(256), 0, stream,
                       boxes, priors, pfo);
    hipLaunchKernelGGL(k_force, dim3(1), dim3(64), 0, stream, pfo, ovp, objp);
    // 35 blocks x: 35*256 row-slots >= 8732 rows (4 rows per 4-lane group)
    hipLaunchKernelGGL(k_ce, dim3(35, BATCH), dim3(256), 0, stream,
                       scores, plocs, boxes, labels, priors, ovp, objp, ce_neg, n_pos, scal);
    hipLaunchKernelGGL(k_topk, dim3(BATCH), dim3(256), 0, stream, ce_neg, n_pos, scal);
    hipLaunchKernelGGL(k_final, dim3(1), dim3(64), 0, stream, n_pos, scal, out);
}

// Round 14
// 227.928 us; speedup vs baseline: 1.0768x; 1.0768x over previous
//
#include <hip/hip_runtime.h>
#include <math.h>
#include <stdint.h>

#define BATCH 64
#define N_OBJ 32
#define NP 8732
#define NC 81
#define THRESH 0.5f
#define NROWS (BATCH * NP)
#define TOTAL4 ((BATCH * NP * NC) / 4)   // 11,316,192
#define STRIDE4 (2048 * 256)             // 524,288

// ---------------------------------------------------------------------------
// ws layout:
//   ovp    : float[NROWS]   best IoU per (image, prior)
//   objp   : int  [NROWS]   argmax object per (image, prior)
//   ce_neg : float[NROWS]   CE of negatives (0 at positives)
//   rowsum : float[NROWS]   sum of exp(scores) per row
//   pfo    : int  [BATCH*N_OBJ]
//   n_pos  : int  [BATCH]
//   scal   : float[3]       {conf_pos, conf_hard_neg, loc_sum}
// ---------------------------------------------------------------------------

__device__ __forceinline__ float iou_box_prior(float x1, float y1, float x2, float y2,
                                               float areaA, float4 pr, float areaB) {
    float iw = fminf(x2, pr.z) - fmaxf(x1, pr.x); iw = fmaxf(iw, 0.f);
    float ih = fminf(y2, pr.w) - fmaxf(y1, pr.y); ih = fmaxf(ih, 0.f);
    float inter = iw * ih;
    return inter / (areaA + areaB - inter);
}

// per (image, prior): best object; also zeroes n_pos/scal/rowsum
__global__ void k_match_prior(const float* __restrict__ boxes,
                              const float* __restrict__ priors,
                              float* __restrict__ ovp, int* __restrict__ objp,
                              int* __restrict__ n_pos, float* __restrict__ scal,
                              float* __restrict__ rowsum) {
    int i = blockIdx.y;
    int t = threadIdx.x;
    int lin = (blockIdx.y * gridDim.x + blockIdx.x) * 256 + t;
    if (lin < NROWS) rowsum[lin] = 0.f;
    if (blockIdx.x == 0 && i == 0) {
        if (t < BATCH) n_pos[t] = 0;
        if (t < 3) scal[t] = 0.f;
    }
    __shared__ float bx[N_OBJ * 4];
    if (t < N_OBJ * 4) bx[t] = boxes[i * N_OBJ * 4 + t];
    __syncthreads();
    int p = blockIdx.x * blockDim.x + t;
    if (p >= NP) return;
    float4 pr = ((const float4*)priors)[p];
    float areaB = (pr.z - pr.x) * (pr.w - pr.y);
    float best = -1.0f; int bestj = 0;
    #pragma unroll
    for (int j = 0; j < N_OBJ; ++j) {
        float x1 = bx[j * 4 + 0], y1 = bx[j * 4 + 1], x2 = bx[j * 4 + 2], y2 = bx[j * 4 + 3];
        float areaA = (x2 - x1) * (y2 - y1);
        float v = iou_box_prior(x1, y1, x2, y2, areaA, pr, areaB);
        if (v > best) { best = v; bestj = j; }   // strict > keeps FIRST max
    }
    ovp[i * NP + p] = best;
    objp[i * NP + p] = bestj;
}

// per (image, object): best prior (first-index tie-break)
__global__ void k_match_obj(const float* __restrict__ boxes,
                            const float* __restrict__ priors,
                            int* __restrict__ pfo) {
    int j = blockIdx.x, i = blockIdx.y;
    const float* bp = boxes + (i * N_OBJ + j) * 4;
    float x1 = bp[0], y1 = bp[1], x2 = bp[2], y2 = bp[3];
    float areaA = (x2 - x1) * (y2 - y1);
    float best = -1.f; int bestp = NP;
    for (int p = threadIdx.x; p < NP; p += blockDim.x) {
        float4 pr = ((const float4*)priors)[p];
        float areaB = (pr.z - pr.x) * (pr.w - pr.y);
        float v = iou_box_prior(x1, y1, x2, y2, areaA, pr, areaB);
        if (v > best) { best = v; bestp = p; }
    }
    __shared__ float sv[256];
    __shared__ int   si[256];
    int t = threadIdx.x;
    sv[t] = best; si[t] = bestp;
    __syncthreads();
    for (int s = 128; s > 0; s >>= 1) {
        if (t < s) {
            float v2 = sv[t + s]; int i2 = si[t + s];
            if (v2 > sv[t] || (v2 == sv[t] && i2 < si[t])) { sv[t] = v2; si[t] = i2; }
        }
        __syncthreads();
    }
    if (t == 0) pfo[i * N_OBJ + j] = si[0];
}

// sequential last-wins forced matches
__global__ void k_force(const int* __restrict__ pfo,
                        float* __restrict__ ovp, int* __restrict__ objp) {
    int i = blockIdx.x * blockDim.x + threadIdx.x;
    if (i >= BATCH) return;
    for (int j = 0; j < N_OBJ; ++j) {
        int p = pfo[i * N_OBJ + j];
        objp[i * NP + p] = j;
        ovp[i * NP + p] = 1.0f;
    }
}

// bwref-shaped segmented sum-of-exp: flat grid-stride float4 stream, 22
// loads/thread in 8/8/6 batches. Per float4: 4 exps, row split; lane's
// overflow folds into successor lane (shfl_up); 6-step segmented scan;
// only segment tails (+lane63 overflow) do global atomicAdd (~740K total).
__global__ void __launch_bounds__(256)
k_sumexp(const float* __restrict__ scores, float* __restrict__ rowsum) {
    int tid  = blockIdx.x * 256 + threadIdx.x;
    int lane = threadIdx.x & 63;
    const float4* s4 = (const float4*)scores;

    #pragma unroll
    for (int jb = 0; jb < 3; ++jb) {
        const int NB = (jb < 2) ? 8 : 6;
        float4 v[8];
        #pragma unroll
        for (int k = 0; k < 8; ++k) {
            if (k < NB) {
                int id = tid + (jb * 8 + k) * STRIDE4;
                int idc = (id < TOTAL4) ? id : (TOTAL4 - 1);
                v[k] = s4[idc];
            }
        }
        #pragma unroll
        for (int k = 0; k < 8; ++k) {
            if (k >= NB) continue;
            int id = tid + (jb * 8 + k) * STRIDE4;
            float wt = (id < TOTAL4) ? 1.f : 0.f;
            int idc = (id < TOTAL4) ? id : (TOTAL4 - 1);
            int E = idc * 4;
            unsigned r = (unsigned)E / 81u;
            int rem = E - (int)(r * 81u);
            float e0 = __expf(v[k].x), e1 = __expf(v[k].y);
            float e2 = __expf(v[k].z), e3 = __expf(v[k].w);
            int q = 81 - rem;                   // elems left in row r (>=1)
            float s_lo, s_hi;
            if (q >= 4)      { s_lo = (e0 + e1) + (e2 + e3); s_hi = 0.f; }
            else if (q == 3) { s_lo = (e0 + e1) + e2;        s_hi = e3; }
            else if (q == 2) { s_lo = e0 + e1;               s_hi = e2 + e3; }
            else             { s_lo = e0;                    s_hi = (e1 + e2) + e3; }
            s_lo *= wt; s_hi *= wt;

            // fold overflow into successor lane (its key is exactly r+1)
            float sh = __shfl_up(s_hi, 1);
            float x = s_lo + ((lane > 0) ? sh : 0.f);
            if (lane == 63 && s_hi != 0.f) atomicAdd(&rowsum[r + 1], s_hi);

            // segmented inclusive scan over (r, x), keys non-decreasing
            unsigned rr = r;
            #pragma unroll
            for (int off = 1; off < 64; off <<= 1) {
                float    xv = __shfl_up(x, off);
                unsigned kv = __shfl_up(rr, off);
                if (lane >= off && kv == rr) x += xv;
            }
            unsigned rn = __shfl_down(rr, 1);
            bool tail = (lane == 63) || (rn != rr);
            if (tail && x != 0.f) atomicAdd(&rowsum[rr], x);
        }
    }
}

// per row: ce = log(rowsum) - score[lab]; positive epilogue; ce_neg write
__global__ void __launch_bounds__(256)
k_finish(const float* __restrict__ scores,
         const float* __restrict__ plocs,
         const float* __restrict__ boxes,
         const int*   __restrict__ labels,
         const float* __restrict__ priors,
         const float* __restrict__ ovp,
         const int*   __restrict__ objp,
         const float* __restrict__ rowsum,
         float* __restrict__ ce_neg,
         int* __restrict__ n_pos, float* __restrict__ scal) {
    int i = blockIdx.y;
    int p = blockIdx.x * 256 + threadIdx.x;
    if (p >= NP) return;
    int gi = i * NP + p;

    int   obj = objp[gi];
    float ov  = ovp[gi];
    int   lab = (ov < THRESH) ? 0 : labels[i * N_OBJ + obj];
    float s    = rowsum[gi];
    float slab = scores[(size_t)gi * NC + lab];
    float ce = __logf(s) - slab;

    if (lab != 0) {
        atomicAdd(&n_pos[i], 1);
        atomicAdd(&scal[0], ce);
        const float* bp = boxes + (i * N_OBJ + obj) * 4;
        float bx1 = bp[0], by1 = bp[1], bx2 = bp[2], by2 = bp[3];
        float bcx = (bx1 + bx2) * 0.5f, bcy = (by1 + by2) * 0.5f;
        float bw = bx2 - bx1, bh = by2 - by1;
        float4 pr = ((const float4*)priors)[p];
        float g0 = (bcx - pr.x) / (pr.z / 10.0f);
        float g1 = (bcy - pr.y) / (pr.w / 10.0f);
        float g2 = logf(bw / pr.z) * 5.0f;
        float g3 = logf(bh / pr.w) * 5.0f;
        const float* pl = plocs + (size_t)gi * 4;
        float ll = fabsf(pl[0] - g0) + fabsf(pl[1] - g1)
                 + fabsf(pl[2] - g2) + fabsf(pl[3] - g3);
        atomicAdd(&scal[2], ll);
        ce_neg[gi] = 0.f;
    } else {
        ce_neg[gi] = ce;
    }
}

// exact top-k sum per row (registers, 31-pass bit-pattern binary search)
__global__ void __launch_bounds__(256)
k_topk(const float* __restrict__ ce_neg,
       const int* __restrict__ n_pos, float* __restrict__ scal) {
    int i = blockIdx.x;
    int t = threadIdx.x;
    float x[35];
    #pragma unroll
    for (int j = 0; j < 35; ++j) {
        int p = t + j * 256;
        x[j] = (p < NP) ? ce_neg[i * NP + p] : 0.f;
    }
    int k = 3 * n_pos[i];
    if (k > NP) k = NP;
    if (k <= 0) return;

    __shared__ int   cnt_s[4];
    __shared__ float sum_s[4];
    unsigned lo = 0u, hi = 0x7F800001u;
    while (hi - lo > 1u) {
        unsigned mid = lo + ((hi - lo) >> 1);
        int c = 0;
        #pragma unroll
        for (int j = 0; j < 35; ++j) c += (__float_as_uint(x[j]) >= mid) ? 1 : 0;
        #pragma unroll
        for (int off = 32; off; off >>= 1) c += __shfl_xor(c, off);
        if ((t & 63) == 0) cnt_s[t >> 6] = c;
        __syncthreads();
        int total = cnt_s[0] + cnt_s[1] + cnt_s[2] + cnt_s[3];
        __syncthreads();
        if (total >= k) lo = mid; else hi = mid;
    }
    float vk = __uint_as_float(lo);

    float s = 0.f; int c = 0;
    #pragma unroll
    for (int j = 0; j < 35; ++j) {
        float v = x[j];
        if (v > vk) { s += v; c++; }
    }
    #pragma unroll
    for (int off = 32; off; off >>= 1) { s += __shfl_xor(s, off); c += __shfl_xor(c, off); }
    if ((t & 63) == 0) { sum_s[t >> 6] = s; cnt_s[t >> 6] = c; }
    __syncthreads();
    if (t == 0) {
        float st = sum_s[0] + sum_s[1] + sum_s[2] + sum_s[3];
        int   ct = cnt_s[0] + cnt_s[1] + cnt_s[2] + cnt_s[3];
        atomicAdd(&scal[1], st + (float)(k - ct) * vk);
    }
}

__global__ void k_final(const int* __restrict__ n_pos,
                        const float* __restrict__ scal, float* __restrict__ out) {
    int t = threadIdx.x;
    int v = (t < BATCH) ? n_pos[t] : 0;
    #pragma unroll
    for (int off = 32; off; off >>= 1) v += __shfl_xor(v, off);
    if (t == 0) {
        float nf = (float)v;
        out[0] = (scal[1] + scal[0]) / nf + scal[2] / (nf * 4.0f);
    }
}

extern "C" void kernel_launch(void* const* d_in, const int* in_sizes, int n_in,
                              void* d_out, int out_size, void* d_ws, size_t ws_size,
                              hipStream_t stream) {
    const float* plocs  = (const float*)d_in[0];
    const float* scores = (const float*)d_in[1];
    const float* boxes  = (const float*)d_in[2];
    const int*   labels = (const int*)d_in[3];
    const float* priors = (const float*)d_in[4];
    float* out = (float*)d_out;

    char* ws = (char*)d_ws;
    size_t bp = (size_t)NROWS * 4;
    float* ovp    = (float*)(ws);
    int*   objp   = (int*)  (ws + bp);
    float* ce_neg = (float*)(ws + 2 * bp);
    float* rowsum = (float*)(ws + 3 * bp);
    int*   pfo    = (int*)  (ws + 4 * bp);
    int*   n_pos  = pfo + BATCH * N_OBJ;
    float* scal   = (float*)(n_pos + BATCH);

    hipLaunchKernelGGL(k_match_prior, dim3((NP + 255) / 256, BATCH), dim3(256), 0, stream,
                       boxes, priors, ovp, objp, n_pos, scal, rowsum);
    hipLaunchKernelGGL(k_sumexp, dim3(2048), dim3(256), 0, stream, scores, rowsum);
    hipLaunchKernelGGL(k_match_obj, dim3(N_OBJ, BATCH), dim3(256), 0, stream,
                       boxes, priors, pfo);
    hipLaunchKernelGGL(k_force, dim3(1), dim3(64), 0, stream, pfo, ovp, objp);
    hipLaunchKernelGGL(k_finish, dim3((NP + 255) / 256, BATCH), dim3(256), 0, stream,
                       scores, plocs, boxes, labels, priors, ovp, objp, rowsum,
                       ce_neg, n_pos, scal);
    hipLaunchKernelGGL(k_topk, dim3(BATCH), dim3(256), 0, stream, ce_neg, n_pos, scal);
    hipLaunchKernelGGL(k_final, dim3(1), dim3(64), 0, stream, n_pos, scal, out);
}